// Round 20
// baseline (247.768 us; speedup 1.0000x reference)
//
#include <hip/hip_runtime.h>
#include <float.h>
#include <math.h>

#define BATCH 16
#define CHANS 65
#define HC 160
#define WC 160
#define HH 1280
#define WW 1280
#define KP 512
#define CAP 8192

// ---- key packing: ascending-sort key == descending score, tie -> lower idx ----
static __device__ __forceinline__ unsigned long long make_key(float f, unsigned idx) {
  unsigned u = __float_as_uint(f);
  u = (u & 0x80000000u) ? ~u : (u | 0x80000000u);   // monotone ascending map
  return ((unsigned long long)(~u) << 32) | (unsigned long long)idx;
}
static __device__ __forceinline__ float key_score(unsigned long long key) {
  unsigned mk = ~(unsigned)(key >> 32);
  unsigned u = (mk & 0x80000000u) ? (mk & 0x7FFFFFFFu) : ~mk;
  return __uint_as_float(u);
}

// ---- P1: softmax over 65 bins (CR f32 exp), drop dustbin, shuffle, border zero ----
__global__ __launch_bounds__(256) void k_softmax_shuffle(const float* __restrict__ hm,
                                                         float* __restrict__ sm) {
  int id = blockIdx.x * 256 + threadIdx.x;
  const int NC = HC * WC;
  int b = id / NC;
  int cell = id - b * NC;
  int hc = cell / WC;
  int wc = cell - hc * WC;
  float* orow = sm + (size_t)b * HH * WW + (size_t)(hc * 8) * WW + wc * 8;

  if (hc < 2 || hc >= HC - 2 || wc < 2 || wc >= WC - 2) {
    float4 z = make_float4(0.f, 0.f, 0.f, 0.f);
#pragma unroll
    for (int r = 0; r < 8; ++r) {
      *(float4*)(orow + (size_t)r * WW) = z;
      *(float4*)(orow + (size_t)r * WW + 4) = z;
    }
    return;
  }

  const float* ibase = hm + (size_t)b * CHANS * NC + cell;
  float v[CHANS];
  float m = -FLT_MAX;
#pragma unroll
  for (int c = 0; c < CHANS; ++c) {
    v[c] = ibase[(size_t)c * NC];
    m = fmaxf(m, v[c]);
  }
  float s = 0.f;
#pragma unroll
  for (int c = 0; c < CHANS; ++c) {
    float d = __fsub_rn(v[c], m);
    v[c] = (float)exp((double)d);   // correctly-rounded f32 exp
    s = __fadd_rn(s, v[c]);         // sequential f32 accumulation
  }
#pragma unroll
  for (int r = 0; r < 8; ++r) {
    float4 q0, q1;
    q0.x = __fdiv_rn(v[r*8+0], s); q0.y = __fdiv_rn(v[r*8+1], s);
    q0.z = __fdiv_rn(v[r*8+2], s); q0.w = __fdiv_rn(v[r*8+3], s);
    q1.x = __fdiv_rn(v[r*8+4], s); q1.y = __fdiv_rn(v[r*8+5], s);
    q1.z = __fdiv_rn(v[r*8+6], s); q1.w = __fdiv_rn(v[r*8+7], s);
    *(float4*)(orow + (size_t)r * WW)     = q0;
    *(float4*)(orow + (size_t)r * WW + 4) = q1;
  }
}

// ---- P2+P3+P4 FUSED: stream sm rows -> on-the-fly 3x3 avg (bitwise R18 order)
// -> vertical 17-max in registers -> LDS -> horizontal 17-max + emit.
// avg buffer eliminated. XCD swizzle: vertical neighbors share an L2. ----
#define CHUNKS 156
__global__ __launch_bounds__(512) void k_avg_vmax_nms(const float* __restrict__ sm,
                                                      int* __restrict__ cnt,
                                                      unsigned long long* __restrict__ cand) {
  __shared__ float lv[8 * WW];      // 40 KiB: vertical-max rows y0..y0+7
  __shared__ float la[8 * WW];      // 40 KiB: avg rows y0..y0+7
  __shared__ int scan[512];
  __shared__ int sbase;
  // XCD-aware swizzle: 2496 blocks = 8 XCDs x 312; give each XCD a contiguous
  // span so vertically-adjacent chunks hit the same L2 for halo rows.
  int wgid = (blockIdx.x & 7) * 312 + (blockIdx.x >> 3);
  int b = wgid / CHUNKS;
  int chunk = wgid % CHUNKS;
  int y0 = 16 + 8 * chunk;
  int tid = threadIdx.x;
  const float* base = sm + (size_t)b * HH * WW;

  if (tid < 320) {
    int x0 = tid * 4;
    // rolling 3-row window of (left, center4, right) sm values
    float lf[3], rt[3];
    float4 c4[3];
    float4 mm[8];
    // rows k2=0..25 -> sm row y = y0-9+k2 (all in [7,1273) -> in-bounds)
#pragma unroll
    for (int k2 = 0; k2 < 26; ++k2) {
      const float* row = base + (size_t)(y0 - 9 + k2) * WW;
      int slot = k2 % 3;
      lf[slot] = (x0 > 0) ? row[x0 - 1] : 0.f;
      c4[slot] = *(const float4*)(row + x0);
      rt[slot] = (x0 + 4 < WW) ? row[x0 + 4] : 0.f;
      if (k2 >= 2) {
        int k = k2 - 10;                 // avg row index rel. y0, in [-8,15]
        // 3x3 sum, rows ascending (dy=-1,0,1), R18 add order per lane
        float a0 = 0.f, a1 = 0.f, a2 = 0.f, a3 = 0.f;
#pragma unroll
        for (int d = 0; d < 3; ++d) {
          int sl = (k2 - 2 + d) % 3;
          float l = lf[sl], r = rt[sl];
          float4 c = c4[sl];
          a0 = __fadd_rn(__fadd_rn(__fadd_rn(a0, l),   c.x), c.y);
          a1 = __fadd_rn(__fadd_rn(__fadd_rn(a1, c.x), c.y), c.z);
          a2 = __fadd_rn(__fadd_rn(__fadd_rn(a2, c.y), c.z), c.w);
          a3 = __fadd_rn(__fadd_rn(__fadd_rn(a3, c.z), c.w), r);
        }
        float4 a4;
        a4.x = __fdiv_rn(a0, 9.0f); a4.y = __fdiv_rn(a1, 9.0f);
        a4.z = __fdiv_rn(a2, 9.0f); a4.w = __fdiv_rn(a3, 9.0f);
        if (k >= 0 && k < 8) *(float4*)(la + k * WW + x0) = a4;
        // accumulate vertical 17-window maxes (fmax assoc -> bitwise same)
#pragma unroll
        for (int rr = 0; rr < 8; ++rr) {
          if (k == rr - 8) mm[rr] = a4;
          else if (k > rr - 8 && k <= rr + 8) {
            mm[rr].x = fmaxf(mm[rr].x, a4.x); mm[rr].y = fmaxf(mm[rr].y, a4.y);
            mm[rr].z = fmaxf(mm[rr].z, a4.z); mm[rr].w = fmaxf(mm[rr].w, a4.w);
          }
        }
      }
    }
#pragma unroll
    for (int rr = 0; rr < 8; ++rr) *(float4*)(lv + rr * WW + x0) = mm[rr];
  }
  __syncthreads();

  // phase B: per-column horizontal 17-max + candidate detection
  unsigned msk0 = 0, msk1 = 0, msk2 = 0;
  int cntl = 0;
#pragma unroll
  for (int k = 0; k < 3; ++k) {
    int x = tid + 512 * k;
    if (x >= 16 && x < 1264) {
      unsigned m = 0;
#pragma unroll
      for (int rr = 0; rr < 8; ++rr) {
        const float* lrow = lv + rr * WW;
        float wm = lrow[x - 8];
#pragma unroll
        for (int j = 1; j < 17; ++j) wm = fmaxf(wm, lrow[x - 8 + j]);
        float c = la[rr * WW + x];
        if (c >= wm) { m |= (1u << rr); cntl++; }
      }
      if (k == 0) msk0 = m; else if (k == 1) msk1 = m; else msk2 = m;
    }
  }

  scan[tid] = cntl;
  __syncthreads();
  for (int off = 1; off < 512; off <<= 1) {
    int v = scan[tid];
    if (tid >= off) v += scan[tid - off];
    __syncthreads();
    scan[tid] = v;
    __syncthreads();
  }
  if (tid == 0) {
    int total = scan[511];
    sbase = total ? atomicAdd(&cnt[b * 16], total) : 0;
  }
  __syncthreads();
  int pos = sbase + scan[tid] - cntl;
#pragma unroll
  for (int k = 0; k < 3; ++k) {
    int x = tid + 512 * k;
    unsigned m = (k == 0) ? msk0 : (k == 1) ? msk1 : msk2;
    while (m) {
      int rr = __ffs(m) - 1;
      m &= m - 1u;
      float c = la[rr * WW + x];
      if (pos < CAP) cand[(size_t)b * CAP + pos] = make_key(c, (unsigned)((y0 + rr) * WW + x));
      pos++;
    }
  }
}

#define CE_ASC(A, B) { unsigned long long _x = s[A], _y = s[B]; \
                       if (_x > _y) { s[A] = _y; s[B] = _x; } }

// ---- P5a: per-chunk bitonic sort (BATCH*8 blocks) ----
__global__ __launch_bounds__(256) void k_sort_chunks(const int* __restrict__ cnt,
                                                     const unsigned long long* __restrict__ cand,
                                                     unsigned long long* __restrict__ srt) {
  __shared__ unsigned long long s[1024];   // 8 KiB
  int b = blockIdx.x >> 3;
  int c = blockIdx.x & 7;
  int tid = threadIdx.x;
  int raw = cnt[b * 16];
  int count = raw > CAP ? CAP : raw;
  int base = c * 1024;
  for (int i = tid; i < 1024; i += 256)
    s[i] = (base + i < count) ? cand[(size_t)b * CAP + base + i] : ~0ULL;
  __syncthreads();
  for (int k = 2; k <= 1024; k <<= 1) {
    for (int j = k >> 1; j > 0; j >>= 1) {
      for (int i = tid; i < 1024; i += 256) {
        int ixj = i ^ j;
        if (ixj > i) {
          unsigned long long a = s[i], d = s[ixj];
          bool up = ((i & k) == 0);
          if ((a > d) == up) { s[i] = d; s[ixj] = a; }
        }
      }
      __syncthreads();
    }
  }
  for (int i = tid; i < 1024; i += 256)
    srt[(size_t)b * CAP + base + i] = s[i];
}

// ---- P5b: truncated bitonic merge tree (top-1024) + canonicalize + output ----
__global__ __launch_bounds__(1024) void k_merge_topk(const int* __restrict__ cnt,
                                                     const unsigned long long* __restrict__ srt,
                                                     float* __restrict__ out) {
  __shared__ unsigned long long s[CAP];   // 64 KiB
  __shared__ unsigned flagw[32];
  int b = blockIdx.x;
  int tid = threadIdx.x;
  int raw = cnt[b * 16];
  int count = raw > CAP ? CAP : raw;
  if (tid < 32) flagw[tid] = 0;

#pragma unroll
  for (int c = 0; c < 8; ++c) {
    unsigned long long v = srt[(size_t)b * CAP + c * 1024 + tid];
    if (c & 1) s[c * 1024 + (1023 - tid)] = v;
    else       s[c * 1024 + tid]          = v;
  }
  __syncthreads();

#pragma unroll
  for (int r = 0; r < 4; ++r) { int i = r * 2048 + tid; CE_ASC(i, i + 1024); }
  __syncthreads();
  for (int j = 512; j >= 1; j >>= 1) {
    for (int t = tid; t < 2048; t += 1024) {
      int r = t >> 9, u = t & 511;
      int i = r * 2048 + (u / j) * (2 * j) + (u % j);
      CE_ASC(i, i + j);
    }
    __syncthreads();
  }
  {
    unsigned long long v1 = s[2048 + 1023 - tid];
    unsigned long long v2 = s[6144 + 1023 - tid];
    s[1024 + tid] = v1;
    s[5120 + tid] = v2;
  }
  __syncthreads();
#pragma unroll
  for (int r = 0; r < 2; ++r) { int i = r * 4096 + tid; CE_ASC(i, i + 1024); }
  __syncthreads();
  for (int j = 512; j >= 1; j >>= 1) {
    int r = tid >> 9, u = tid & 511;
    int i = r * 4096 + (u / j) * (2 * j) + (u % j);
    CE_ASC(i, i + j);
    __syncthreads();
  }
  s[1024 + tid] = s[4096 + 1023 - tid];
  __syncthreads();
  CE_ASC(tid, tid + 1024);
  __syncthreads();
  for (int j = 512; j >= 1; j >>= 1) {
    if (tid < 512) {
      int i = (tid / j) * (2 * j) + (tid % j);
      CE_ASC(i, i + j);
    }
    __syncthreads();
  }

  // NEAR-TIE canonicalization (measured R11-R13): parallel detect + serial fix
  int lim = count < 520 ? count : 520;
  if (tid + 1 < lim) {
    unsigned u0 = ~(unsigned)(s[tid] >> 32);
    unsigned u1 = ~(unsigned)(s[tid + 1] >> 32);
    unsigned i0 = (unsigned)(s[tid] & 0xFFFFFFFFu);
    unsigned i1 = (unsigned)(s[tid + 1] & 0xFFFFFFFFu);
    if (u0 - u1 <= 1u && i0 > i1) atomicOr(&flagw[tid >> 5], 1u << (tid & 31));
  }
  __syncthreads();
  if (tid == 0) {
    int resume = 0;
    for (int w = 0; w < 17; ++w) {
      unsigned f = flagw[w];
      while (f) {
        int p = w * 32 + (__ffs(f) - 1);
        f &= f - 1u;
        if (p < resume) continue;
        int i = p;
        while (i + 1 < lim) {
          unsigned u0 = ~(unsigned)(s[i] >> 32);
          unsigned u1 = ~(unsigned)(s[i + 1] >> 32);
          unsigned i0 = (unsigned)(s[i] & 0xFFFFFFFFu);
          unsigned i1 = (unsigned)(s[i + 1] & 0xFFFFFFFFu);
          if (u0 - u1 <= 1u && i0 > i1) {
            unsigned long long t = s[i]; s[i] = s[i + 1]; s[i + 1] = t;
            ++i;
          } else break;
        }
        resume = i + 1;
      }
    }
  }
  __syncthreads();

  if (tid < KP) {
    if (tid < count) {
      unsigned long long key = s[tid];
      unsigned idx = (unsigned)(key & 0xFFFFFFFFu);
      float score = key_score(key);
      float xf = (float)(idx % WW);
      float yf = (float)(idx / WW);
      out[((size_t)b * KP + tid) * 2 + 0] = __fdiv_rn(xf, 1279.0f);
      out[((size_t)b * KP + tid) * 2 + 1] = __fdiv_rn(yf, 1279.0f);
      out[(size_t)BATCH * KP * 2 + (size_t)b * KP + tid] = score;
    } else {
      out[((size_t)b * KP + tid) * 2 + 0] = 2.0f;
      out[((size_t)b * KP + tid) * 2 + 1] = 2.0f;
      out[(size_t)BATCH * KP * 2 + (size_t)b * KP + tid] = 0.0f;
    }
    if (tid == 0 && raw > CAP) {
      out[((size_t)b * KP) * 2 + 0] = 3.0f;
      out[((size_t)b * KP) * 2 + 1] = 3.0f;
    }
  }
}

extern "C" void kernel_launch(void* const* d_in, const int* in_sizes, int n_in,
                              void* d_out, int out_size, void* d_ws, size_t ws_size,
                              hipStream_t stream) {
  const float* hm = (const float*)d_in[0];
  float* out = (float*)d_out;
  char* ws = (char*)d_ws;

  int* cnt = (int*)ws;                                               // 1 KiB
  unsigned long long* cand = (unsigned long long*)(ws + 1024);       // 1 MiB
  unsigned long long* srt  = cand + (size_t)BATCH * CAP;             // 1 MiB
  float* sm  = (float*)((char*)srt + (size_t)BATCH * CAP * 8);       // 100 MiB

  hipMemsetAsync(cnt, 0, 1024, stream);

  k_softmax_shuffle<<<BATCH * HC * WC / 256, 256, 0, stream>>>(hm, sm);
  k_avg_vmax_nms<<<BATCH * CHUNKS, 512, 0, stream>>>(sm, cnt, cand);
  k_sort_chunks<<<BATCH * 8, 256, 0, stream>>>(cnt, cand, srt);
  k_merge_topk<<<BATCH, 1024, 0, stream>>>(cnt, srt, out);
}

// Round 21
// 237.356 us; speedup vs baseline: 1.0439x; 1.0439x over previous
//
#include <hip/hip_runtime.h>
#include <float.h>
#include <math.h>

#define BATCH 16
#define CHANS 65
#define HC 160
#define WC 160
#define HH 1280
#define WW 1280
#define KP 512
#define CAP 8192

// ---- key packing: ascending-sort key == descending score, tie -> lower idx ----
static __device__ __forceinline__ unsigned long long make_key(float f, unsigned idx) {
  unsigned u = __float_as_uint(f);
  u = (u & 0x80000000u) ? ~u : (u | 0x80000000u);   // monotone ascending map
  return ((unsigned long long)(~u) << 32) | (unsigned long long)idx;
}
static __device__ __forceinline__ float key_score(unsigned long long key) {
  unsigned mk = ~(unsigned)(key >> 32);
  unsigned u = (mk & 0x80000000u) ? (mk & 0x7FFFFFFFu) : ~mk;
  return __uint_as_float(u);
}

// ---- P1: softmax over 65 bins (CR f32 exp), drop dustbin, shuffle, border zero ----
__global__ __launch_bounds__(256) void k_softmax_shuffle(const float* __restrict__ hm,
                                                         float* __restrict__ sm) {
  int id = blockIdx.x * 256 + threadIdx.x;
  const int NC = HC * WC;
  int b = id / NC;
  int cell = id - b * NC;
  int hc = cell / WC;
  int wc = cell - hc * WC;
  float* orow = sm + (size_t)b * HH * WW + (size_t)(hc * 8) * WW + wc * 8;

  if (hc < 2 || hc >= HC - 2 || wc < 2 || wc >= WC - 2) {
    float4 z = make_float4(0.f, 0.f, 0.f, 0.f);
#pragma unroll
    for (int r = 0; r < 8; ++r) {
      *(float4*)(orow + (size_t)r * WW) = z;
      *(float4*)(orow + (size_t)r * WW + 4) = z;
    }
    return;
  }

  const float* ibase = hm + (size_t)b * CHANS * NC + cell;
  float v[CHANS];
  float m = -FLT_MAX;
#pragma unroll
  for (int c = 0; c < CHANS; ++c) {
    v[c] = ibase[(size_t)c * NC];
    m = fmaxf(m, v[c]);
  }
  float s = 0.f;
#pragma unroll
  for (int c = 0; c < CHANS; ++c) {
    float d = __fsub_rn(v[c], m);
    v[c] = (float)exp((double)d);   // correctly-rounded f32 exp
    s = __fadd_rn(s, v[c]);         // sequential f32 accumulation
  }
#pragma unroll
  for (int r = 0; r < 8; ++r) {
    float4 q0, q1;
    q0.x = __fdiv_rn(v[r*8+0], s); q0.y = __fdiv_rn(v[r*8+1], s);
    q0.z = __fdiv_rn(v[r*8+2], s); q0.w = __fdiv_rn(v[r*8+3], s);
    q1.x = __fdiv_rn(v[r*8+4], s); q1.y = __fdiv_rn(v[r*8+5], s);
    q1.z = __fdiv_rn(v[r*8+6], s); q1.w = __fdiv_rn(v[r*8+7], s);
    *(float4*)(orow + (size_t)r * WW)     = q0;
    *(float4*)(orow + (size_t)r * WW + 4) = q1;
  }
}

// ---- P2+P3+P4 FUSED v2: 320 threads, 78.5 KB LDS -> 2 blocks/CU.
// Streams sm rows -> 3x3 sums (bitwise R18 add order) -> vertical 17-max on
// SUMS (divide once at end: RN(x/9) monotone => bitwise-identical compares)
// -> LDS -> horizontal 17-max + emit. Shuffle-based scan, one atomic/block. ----
#define CHUNKS 156
#define LVW 1264   // lv cols [8,1272)
#define LAW 1248   // la cols [16,1264)
__global__ __launch_bounds__(320) void k_avg_vmax_nms(const float* __restrict__ sm,
                                                      int* __restrict__ cnt,
                                                      unsigned long long* __restrict__ cand) {
  __shared__ float lv[8 * LVW];     // 39.5 KiB: vmax-of-sums/9, rows y0..y0+7
  __shared__ float la[8 * LAW];     // 39.0 KiB: avg rows y0..y0+7
  __shared__ int wsum[5], woff[5];
  __shared__ int sbase;
  // XCD swizzle: 2496 blocks = 8 XCDs x 312 -> vertical neighbors share an L2
  int wgid = (blockIdx.x & 7) * 312 + (blockIdx.x >> 3);
  int b = wgid / CHUNKS;
  int chunk = wgid % CHUNKS;
  int y0 = 16 + 8 * chunk;
  int tid = threadIdx.x;
  int wv = tid >> 6, lane = tid & 63;
  const float* base = sm + (size_t)b * HH * WW;

  // ---- phase A: all 320 threads, 4 cols each ----
  {
    int x0 = tid * 4;
    float lf[3], rt[3];
    float4 c4[3];
    float4 mm[8];
#pragma unroll
    for (int k2 = 0; k2 < 26; ++k2) {
      const float* row = base + (size_t)(y0 - 9 + k2) * WW;
      int slot = k2 % 3;
      lf[slot] = (x0 > 0) ? row[x0 - 1] : 0.f;
      c4[slot] = *(const float4*)(row + x0);
      rt[slot] = (x0 + 4 < WW) ? row[x0 + 4] : 0.f;
      if (k2 >= 2) {
        int k = k2 - 10;                 // sum-row index rel. y0, in [-8,15]
        float a0 = 0.f, a1 = 0.f, a2 = 0.f, a3 = 0.f;
#pragma unroll
        for (int d = 0; d < 3; ++d) {
          int sl = (k2 - 2 + d) % 3;
          float l = lf[sl], r = rt[sl];
          float4 c = c4[sl];
          a0 = __fadd_rn(__fadd_rn(__fadd_rn(a0, l),   c.x), c.y);
          a1 = __fadd_rn(__fadd_rn(__fadd_rn(a1, c.x), c.y), c.z);
          a2 = __fadd_rn(__fadd_rn(__fadd_rn(a2, c.y), c.z), c.w);
          a3 = __fadd_rn(__fadd_rn(__fadd_rn(a3, c.z), c.w), r);
        }
        float4 s4 = make_float4(a0, a1, a2, a3);
        if (k >= 0 && k < 8 && x0 >= 16 && x0 <= 1260) {
          float4 a4;
          a4.x = __fdiv_rn(s4.x, 9.0f); a4.y = __fdiv_rn(s4.y, 9.0f);
          a4.z = __fdiv_rn(s4.z, 9.0f); a4.w = __fdiv_rn(s4.w, 9.0f);
          *(float4*)(la + k * LAW + (x0 - 16)) = a4;
        }
        // vertical 17-window max on raw sums (fmax assoc, monotone /9 later)
#pragma unroll
        for (int rr = 0; rr < 8; ++rr) {
          if (k == rr - 8) mm[rr] = s4;
          else if (k > rr - 8 && k <= rr + 8) {
            mm[rr].x = fmaxf(mm[rr].x, s4.x); mm[rr].y = fmaxf(mm[rr].y, s4.y);
            mm[rr].z = fmaxf(mm[rr].z, s4.z); mm[rr].w = fmaxf(mm[rr].w, s4.w);
          }
        }
      }
    }
    if (x0 >= 8 && x0 <= 1268) {
#pragma unroll
      for (int rr = 0; rr < 8; ++rr) {
        float4 o;
        o.x = __fdiv_rn(mm[rr].x, 9.0f); o.y = __fdiv_rn(mm[rr].y, 9.0f);
        o.z = __fdiv_rn(mm[rr].z, 9.0f); o.w = __fdiv_rn(mm[rr].w, 9.0f);
        *(float4*)(lv + rr * LVW + (x0 - 8)) = o;
      }
    }
  }
  __syncthreads();

  // ---- phase B: per-column horizontal 17-max + candidate detection ----
  unsigned msk0 = 0, msk1 = 0, msk2 = 0, msk3 = 0;
  int cntl = 0;
#pragma unroll
  for (int k = 0; k < 4; ++k) {
    int x = 16 + tid + 320 * k;
    if (x < 1264) {
      unsigned m = 0;
#pragma unroll
      for (int rr = 0; rr < 8; ++rr) {
        const float* lrow = lv + rr * LVW + (x - 16);   // window cols x-8..x+8
        float wm = lrow[0];
#pragma unroll
        for (int j = 1; j < 17; ++j) wm = fmaxf(wm, lrow[j]);
        float c = la[rr * LAW + (x - 16)];
        if (c >= wm) { m |= (1u << rr); cntl++; }
      }
      if (k == 0) msk0 = m; else if (k == 1) msk1 = m;
      else if (k == 2) msk2 = m; else msk3 = m;
    }
  }

  // ---- shuffle-based block scan, one atomic per block ----
  int inc = cntl;
#pragma unroll
  for (int off = 1; off < 64; off <<= 1) {
    int t = __shfl_up(inc, off, 64);
    if (lane >= off) inc += t;
  }
  if (lane == 63) wsum[wv] = inc;
  __syncthreads();
  if (tid == 0) {
    int acc = 0;
#pragma unroll
    for (int w = 0; w < 5; ++w) { woff[w] = acc; acc += wsum[w]; }
    sbase = acc ? atomicAdd(&cnt[b * 16], acc) : 0;
  }
  __syncthreads();
  int pos = sbase + woff[wv] + inc - cntl;
#pragma unroll
  for (int k = 0; k < 4; ++k) {
    int x = 16 + tid + 320 * k;
    unsigned m = (k == 0) ? msk0 : (k == 1) ? msk1 : (k == 2) ? msk2 : msk3;
    while (m) {
      int rr = __ffs(m) - 1;
      m &= m - 1u;
      float c = la[rr * LAW + (x - 16)];
      if (pos < CAP) cand[(size_t)b * CAP + pos] = make_key(c, (unsigned)((y0 + rr) * WW + x));
      pos++;
    }
  }
}

#define CE_ASC(A, B) { unsigned long long _x = s[A], _y = s[B]; \
                       if (_x > _y) { s[A] = _y; s[B] = _x; } }

// ---- P5a: per-chunk bitonic sort (BATCH*8 blocks) ----
__global__ __launch_bounds__(256) void k_sort_chunks(const int* __restrict__ cnt,
                                                     const unsigned long long* __restrict__ cand,
                                                     unsigned long long* __restrict__ srt) {
  __shared__ unsigned long long s[1024];   // 8 KiB
  int b = blockIdx.x >> 3;
  int c = blockIdx.x & 7;
  int tid = threadIdx.x;
  int raw = cnt[b * 16];
  int count = raw > CAP ? CAP : raw;
  int base = c * 1024;
  for (int i = tid; i < 1024; i += 256)
    s[i] = (base + i < count) ? cand[(size_t)b * CAP + base + i] : ~0ULL;
  __syncthreads();
  for (int k = 2; k <= 1024; k <<= 1) {
    for (int j = k >> 1; j > 0; j >>= 1) {
      for (int i = tid; i < 1024; i += 256) {
        int ixj = i ^ j;
        if (ixj > i) {
          unsigned long long a = s[i], d = s[ixj];
          bool up = ((i & k) == 0);
          if ((a > d) == up) { s[i] = d; s[ixj] = a; }
        }
      }
      __syncthreads();
    }
  }
  for (int i = tid; i < 1024; i += 256)
    srt[(size_t)b * CAP + base + i] = s[i];
}

// ---- P5b: truncated bitonic merge tree (top-1024) + canonicalize + output ----
__global__ __launch_bounds__(1024) void k_merge_topk(const int* __restrict__ cnt,
                                                     const unsigned long long* __restrict__ srt,
                                                     float* __restrict__ out) {
  __shared__ unsigned long long s[CAP];   // 64 KiB
  __shared__ unsigned flagw[32];
  int b = blockIdx.x;
  int tid = threadIdx.x;
  int raw = cnt[b * 16];
  int count = raw > CAP ? CAP : raw;
  if (tid < 32) flagw[tid] = 0;

#pragma unroll
  for (int c = 0; c < 8; ++c) {
    unsigned long long v = srt[(size_t)b * CAP + c * 1024 + tid];
    if (c & 1) s[c * 1024 + (1023 - tid)] = v;
    else       s[c * 1024 + tid]          = v;
  }
  __syncthreads();

#pragma unroll
  for (int r = 0; r < 4; ++r) { int i = r * 2048 + tid; CE_ASC(i, i + 1024); }
  __syncthreads();
  for (int j = 512; j >= 1; j >>= 1) {
    for (int t = tid; t < 2048; t += 1024) {
      int r = t >> 9, u = t & 511;
      int i = r * 2048 + (u / j) * (2 * j) + (u % j);
      CE_ASC(i, i + j);
    }
    __syncthreads();
  }
  {
    unsigned long long v1 = s[2048 + 1023 - tid];
    unsigned long long v2 = s[6144 + 1023 - tid];
    s[1024 + tid] = v1;
    s[5120 + tid] = v2;
  }
  __syncthreads();
#pragma unroll
  for (int r = 0; r < 2; ++r) { int i = r * 4096 + tid; CE_ASC(i, i + 1024); }
  __syncthreads();
  for (int j = 512; j >= 1; j >>= 1) {
    int r = tid >> 9, u = tid & 511;
    int i = r * 4096 + (u / j) * (2 * j) + (u % j);
    CE_ASC(i, i + j);
    __syncthreads();
  }
  s[1024 + tid] = s[4096 + 1023 - tid];
  __syncthreads();
  CE_ASC(tid, tid + 1024);
  __syncthreads();
  for (int j = 512; j >= 1; j >>= 1) {
    if (tid < 512) {
      int i = (tid / j) * (2 * j) + (tid % j);
      CE_ASC(i, i + j);
    }
    __syncthreads();
  }

  // NEAR-TIE canonicalization (measured R11-R13): parallel detect + serial fix
  int lim = count < 520 ? count : 520;
  if (tid + 1 < lim) {
    unsigned u0 = ~(unsigned)(s[tid] >> 32);
    unsigned u1 = ~(unsigned)(s[tid + 1] >> 32);
    unsigned i0 = (unsigned)(s[tid] & 0xFFFFFFFFu);
    unsigned i1 = (unsigned)(s[tid + 1] & 0xFFFFFFFFu);
    if (u0 - u1 <= 1u && i0 > i1) atomicOr(&flagw[tid >> 5], 1u << (tid & 31));
  }
  __syncthreads();
  if (tid == 0) {
    int resume = 0;
    for (int w = 0; w < 17; ++w) {
      unsigned f = flagw[w];
      while (f) {
        int p = w * 32 + (__ffs(f) - 1);
        f &= f - 1u;
        if (p < resume) continue;
        int i = p;
        while (i + 1 < lim) {
          unsigned u0 = ~(unsigned)(s[i] >> 32);
          unsigned u1 = ~(unsigned)(s[i + 1] >> 32);
          unsigned i0 = (unsigned)(s[i] & 0xFFFFFFFFu);
          unsigned i1 = (unsigned)(s[i + 1] & 0xFFFFFFFFu);
          if (u0 - u1 <= 1u && i0 > i1) {
            unsigned long long t = s[i]; s[i] = s[i + 1]; s[i + 1] = t;
            ++i;
          } else break;
        }
        resume = i + 1;
      }
    }
  }
  __syncthreads();

  if (tid < KP) {
    if (tid < count) {
      unsigned long long key = s[tid];
      unsigned idx = (unsigned)(key & 0xFFFFFFFFu);
      float score = key_score(key);
      float xf = (float)(idx % WW);
      float yf = (float)(idx / WW);
      out[((size_t)b * KP + tid) * 2 + 0] = __fdiv_rn(xf, 1279.0f);
      out[((size_t)b * KP + tid) * 2 + 1] = __fdiv_rn(yf, 1279.0f);
      out[(size_t)BATCH * KP * 2 + (size_t)b * KP + tid] = score;
    } else {
      out[((size_t)b * KP + tid) * 2 + 0] = 2.0f;
      out[((size_t)b * KP + tid) * 2 + 1] = 2.0f;
      out[(size_t)BATCH * KP * 2 + (size_t)b * KP + tid] = 0.0f;
    }
    if (tid == 0 && raw > CAP) {
      out[((size_t)b * KP) * 2 + 0] = 3.0f;
      out[((size_t)b * KP) * 2 + 1] = 3.0f;
    }
  }
}

extern "C" void kernel_launch(void* const* d_in, const int* in_sizes, int n_in,
                              void* d_out, int out_size, void* d_ws, size_t ws_size,
                              hipStream_t stream) {
  const float* hm = (const float*)d_in[0];
  float* out = (float*)d_out;
  char* ws = (char*)d_ws;

  int* cnt = (int*)ws;                                               // 1 KiB
  unsigned long long* cand = (unsigned long long*)(ws + 1024);       // 1 MiB
  unsigned long long* srt  = cand + (size_t)BATCH * CAP;             // 1 MiB
  float* sm  = (float*)((char*)srt + (size_t)BATCH * CAP * 8);       // 100 MiB

  hipMemsetAsync(cnt, 0, 1024, stream);

  k_softmax_shuffle<<<BATCH * HC * WC / 256, 256, 0, stream>>>(hm, sm);
  k_avg_vmax_nms<<<BATCH * CHUNKS, 320, 0, stream>>>(sm, cnt, cand);
  k_sort_chunks<<<BATCH * 8, 256, 0, stream>>>(cnt, cand, srt);
  k_merge_topk<<<BATCH, 1024, 0, stream>>>(cnt, srt, out);
}